// Round 1
// baseline (1371.408 us; speedup 1.0000x reference)
//
#include <hip/hip_runtime.h>
#include <math.h>

#define NSEQ 4096
#define TQL 48
#define EDIM 64
#define NH 4
#define HD 16
#define TN 288
#define EPSF 1e-5f

__device__ __forceinline__ float wave_sum64(float v) {
    v += __shfl_xor(v, 1, 64);
    v += __shfl_xor(v, 2, 64);
    v += __shfl_xor(v, 4, 64);
    v += __shfl_xor(v, 8, 64);
    v += __shfl_xor(v, 16, 64);
    v += __shfl_xor(v, 32, 64);
    return v;
}

// LDS pool layout (floats), 16384 total = 64 KB -> 2 blocks/CU:
//   Q   [0,3072)     : q = query + temb     (kept for LN1 residual)
//   B1  [3072,6144)  : k -> kp -> attn_out(o)
//   B2  [6144,9216)  : v -> vp -> hj (FF hidden tile)
//   B3  [9216,12288) : qp -> x (LN1 output)
//   WB  [12288,16384): Wq/Wk/Wv (768) -> WoT -> W1 tile -> W2 tile (rot-swizzled)
__global__ __launch_bounds__(256, 2)
void ttrans_kernel(const float* __restrict__ value,
                   const float* __restrict__ keys,
                   const float* __restrict__ query,
                   const float* __restrict__ Wv,
                   const float* __restrict__ Wk,
                   const float* __restrict__ Wq,
                   const float* __restrict__ Wo,
                   const float* __restrict__ bo,
                   const float* __restrict__ temb,
                   const float* __restrict__ ln1g,
                   const float* __restrict__ ln1b,
                   const float* __restrict__ ln2g,
                   const float* __restrict__ ln2b,
                   const float* __restrict__ W1,
                   const float* __restrict__ b1,
                   const float* __restrict__ W2,
                   const float* __restrict__ b2,
                   const int* __restrict__ tqp,
                   float* __restrict__ out)
{
    __shared__ __align__(16) float sp[16384];
    float* Qs = sp;
    float* B1 = sp + 3072;
    float* B2 = sp + 6144;
    float* B3 = sp + 9216;
    float* WB = sp + 12288;

    const int tid = threadIdx.x;
    const int n = blockIdx.x;
    const size_t base = (size_t)n * (TQL * EDIM);
    const int tqv = *tqp;
    const int laneE = tid & 63;
    const int wv = tid >> 6;   // wave id 0..3

    // ---- Stage 0: Wq/Wk/Wv into WB (Wv @0, Wk @256, Wq @512)
    if (tid < 256) {
        WB[tid]       = Wv[tid];
        WB[256 + tid] = Wk[tid];
        WB[512 + tid] = Wq[tid];
    }
    // ---- Stage 1: load q,k (+temb) and v
    for (int i = tid; i < 3072; i += 256) {
        int t = i >> 6, e = i & 63;
        int ti = ((tqv % TN) + TN + t) % TN;
        float tv = temb[ti * EDIM + e];
        Qs[i] = query[base + i] + tv;
        B1[i] = keys[base + i] + tv;
        B2[i] = value[base + i];
    }
    __syncthreads();

    // ---- Stage 2: per-head projections (x @ W.T), in-place for k,v; qp -> B3
    float kpv[16], vpv[16];
    const int t2 = tid >> 2, h2 = tid & 3;
    if (tid < 192) {
        const int ro = t2 * 64 + h2 * 16;
        float qr[16], kr[16], vr[16];
        #pragma unroll
        for (int d = 0; d < 16; ++d) {
            qr[d] = Qs[ro + d]; kr[d] = B1[ro + d]; vr[d] = B2[ro + d];
        }
        #pragma unroll
        for (int e = 0; e < 16; ++e) {
            float aq = 0.f, ak = 0.f, av = 0.f;
            #pragma unroll
            for (int d = 0; d < 16; ++d) {
                aq += qr[d] * WB[512 + e * 16 + d];
                ak += kr[d] * WB[256 + e * 16 + d];
                av += vr[d] * WB[      e * 16 + d];
            }
            B3[ro + e] = aq;   // qp (B3 unused so far)
            kpv[e] = ak; vpv[e] = av;
        }
    }
    __syncthreads();
    if (tid < 192) {
        const int ro = t2 * 64 + h2 * 16;
        #pragma unroll
        for (int e = 0; e < 16; ++e) { B1[ro + e] = kpv[e]; B2[ro + e] = vpv[e]; }
    }
    __syncthreads();

    // ---- Load WoT into WB, rotation-swizzled: Wo[e][e2] at WB[e2*64 + ((e+e2)&63)]
    // (Wqkv in WB is dead after stage 2.)
    for (int i = tid; i < 4096; i += 256) {
        int e = i >> 6, e2 = i & 63;
        WB[e2 * 64 + ((e + e2) & 63)] = Wo[i];
    }

    // ---- Stage 3: attention. thread = (t,h), t=tid>>2, h=tid&3 (192 active)
    float att[48];
    const int t3 = tid >> 2, h3 = tid & 3;
    if (tid < 192) {
        const float4* q4 = reinterpret_cast<const float4*>(B3 + (t3 * 64 + h3 * 16));
        const float4 qa = q4[0], qb = q4[1], qc = q4[2], qd = q4[3];
        #pragma unroll
        for (int k = 0; k < 48; ++k) {
            const float4* k4 = reinterpret_cast<const float4*>(B1 + (k * 64 + h3 * 16));
            float4 ka = k4[0], kb = k4[1], kc = k4[2], kd = k4[3];
            float s = qa.x*ka.x + qa.y*ka.y + qa.z*ka.z + qa.w*ka.w
                    + qb.x*kb.x + qb.y*kb.y + qb.z*kb.z + qb.w*kb.w
                    + qc.x*kc.x + qc.y*kc.y + qc.z*kc.z + qc.w*kc.w
                    + qd.x*kd.x + qd.y*kd.y + qd.z*kd.z + qd.w*kd.w;
            // reference: masked -> -1e6 BEFORE scale+clamp -> clamps to -5 and
            // STILL participates in softmax (exp(-5-m) weight), reproduce exactly
            float ev = (k <= t3) ? s : -1e6f;
            ev *= 0.125f;                       // 1/sqrt(64)
            ev = fminf(5.0f, fmaxf(-5.0f, ev));
            att[k] = ev;
        }
        float m = att[0];
        #pragma unroll
        for (int k = 1; k < 48; ++k) m = fmaxf(m, att[k]);
        float ssum = 0.0f;
        #pragma unroll
        for (int k = 0; k < 48; ++k) { float p = expf(att[k] - m); att[k] = p; ssum += p; }
        float inv = 1.0f / ssum;
        #pragma unroll
        for (int k = 0; k < 48; ++k) att[k] *= inv;
    }
    __syncthreads();   // kp/qp reads done; WoT load visible later
    if (tid < 192) {
        float4 oa = {0,0,0,0}, ob = {0,0,0,0}, oc = {0,0,0,0}, od = {0,0,0,0};
        #pragma unroll
        for (int k = 0; k < 48; ++k) {
            const float4* v4 = reinterpret_cast<const float4*>(B2 + (k * 64 + h3 * 16));
            float4 va = v4[0], vb = v4[1], vc = v4[2], vd = v4[3];
            float p = att[k];
            oa.x += p*va.x; oa.y += p*va.y; oa.z += p*va.z; oa.w += p*va.w;
            ob.x += p*vb.x; ob.y += p*vb.y; ob.z += p*vb.z; ob.w += p*vb.w;
            oc.x += p*vc.x; oc.y += p*vc.y; oc.z += p*vc.z; oc.w += p*vc.w;
            od.x += p*vd.x; od.y += p*vd.y; od.z += p*vd.z; od.w += p*vd.w;
        }
        float4* o4 = reinterpret_cast<float4*>(B1 + (t3 * 64 + h3 * 16));
        o4[0] = oa; o4[1] = ob; o4[2] = oc; o4[3] = od;   // o overwrites kp
    }
    __syncthreads();

    // ---- Stage 4: out2 = o @ Wo.T + bo ; x = LN1(out2 + q) -> B3
    // wave w owns rows t = w*12 .. w*12+11 ; lane = e. Row is exactly one wave
    // -> LN via shfl reductions, no LDS.
    const float bo_r = bo[laneE];
    const float g1 = ln1g[laneE], be1 = ln1b[laneE];
    const float g2 = ln2g[laneE], be2 = ln2b[laneE];
    const float b2_r = b2[laneE];
    for (int it = 0; it < 12; ++it) {
        int t = wv * 12 + it;
        float a = bo_r;
        #pragma unroll 8
        for (int e2 = 0; e2 < 64; ++e2)
            a += B1[t * 64 + e2] * WB[e2 * 64 + ((laneE + e2) & 63)];
        float vv = a + Qs[t * 64 + laneE];
        float mu = wave_sum64(vv) * (1.0f / 64.0f);
        float d = vv - mu;
        float var = wave_sum64(d * d) * (1.0f / 64.0f);
        B3[t * 64 + laneE] = d * rsqrtf(var + EPSF) * g1 + be1;
    }
    __syncthreads();

    // ---- FF: y = relu(x@W1.T + b1)@W2.T + b2, tiled over j in 4 blocks of 64
    float yacc[12];
    #pragma unroll
    for (int it = 0; it < 12; ++it) yacc[it] = b2_r;
    const int jj = laneE;
    for (int jb = 0; jb < 4; ++jb) {
        // W1 tile transposed+rotated: W1[jb*64+j][e] at WB[e*64 + ((j+e)&63)]
        for (int i = tid; i < 4096; i += 256) {
            int j = i >> 6, e = i & 63;
            WB[e * 64 + ((j + e) & 63)] = W1[(jb * 64 + j) * 64 + e];
        }
        float b1r = b1[jb * 64 + jj];
        __syncthreads();
        // FF1: hj[t][jj] = relu(b1 + sum_e x[t,e] * W1[j,e]) -> B2
        for (int it = 0; it < 12; ++it) {
            int t = wv * 12 + it;
            float a = b1r;
            #pragma unroll 8
            for (int e = 0; e < 64; ++e)
                a += B3[t * 64 + e] * WB[e * 64 + ((jj + e) & 63)];
            B2[t * 64 + jj] = fmaxf(a, 0.0f);
        }
        __syncthreads();
        // W2 tile: W2[e][jb*64+j] at WB[j*64 + ((e+j)&63)]
        for (int i = tid; i < 4096; i += 256) {
            int e = i >> 6, j = i & 63;
            WB[j * 64 + ((e + j) & 63)] = W2[e * 256 + jb * 64 + j];
        }
        __syncthreads();
        // FF2: y[t][e] += sum_j hj[t,j] * W2[e,j]
        for (int it = 0; it < 12; ++it) {
            int t = wv * 12 + it;
            float a = yacc[it];
            #pragma unroll 8
            for (int j = 0; j < 64; ++j)
                a += B2[t * 64 + j] * WB[j * 64 + ((laneE + j) & 63)];
            yacc[it] = a;
        }
        __syncthreads();
    }

    // ---- LN2(ff + x) -> out
    for (int it = 0; it < 12; ++it) {
        int t = wv * 12 + it;
        float vv = yacc[it] + B3[t * 64 + laneE];
        float mu = wave_sum64(vv) * (1.0f / 64.0f);
        float d = vv - mu;
        float var = wave_sum64(d * d) * (1.0f / 64.0f);
        out[base + t * 64 + laneE] = d * rsqrtf(var + EPSF) * g2 + be2;
    }
}

extern "C" void kernel_launch(void* const* d_in, const int* in_sizes, int n_in,
                              void* d_out, int out_size, void* d_ws, size_t ws_size,
                              hipStream_t stream) {
    const float* value = (const float*)d_in[0];
    const float* keys  = (const float*)d_in[1];
    const float* query = (const float*)d_in[2];
    const float* Wv    = (const float*)d_in[3];
    const float* Wk    = (const float*)d_in[4];
    const float* Wq    = (const float*)d_in[5];
    const float* Wo    = (const float*)d_in[6];
    const float* bo    = (const float*)d_in[7];
    const float* temb  = (const float*)d_in[8];
    const float* ln1g  = (const float*)d_in[9];
    const float* ln1b  = (const float*)d_in[10];
    const float* ln2g  = (const float*)d_in[11];
    const float* ln2b  = (const float*)d_in[12];
    const float* W1    = (const float*)d_in[13];
    const float* b1    = (const float*)d_in[14];
    const float* W2    = (const float*)d_in[15];
    const float* b2    = (const float*)d_in[16];
    const int*   tq    = (const int*)d_in[17];
    float* outp = (float*)d_out;

    hipLaunchKernelGGL(ttrans_kernel, dim3(NSEQ), dim3(256), 0, stream,
                       value, keys, query, Wv, Wk, Wq, Wo, bo, temb,
                       ln1g, ln1b, ln2g, ln2b, W1, b1, W2, b2, tq, outp);
}

// Round 2
// 189.346 us; speedup vs baseline: 7.2429x; 7.2429x over previous
//
#include <hip/hip_runtime.h>
#include <hip/hip_bf16.h>
#include <math.h>

#define NSEQ 4096
#define TN 288
#define EPSF 1e-5f

typedef short bf16x8 __attribute__((ext_vector_type(8)));
typedef float f32x4 __attribute__((ext_vector_type(4)));

// ---- LDS pool map (bytes / short-index / float-index) ----
// qf32  [0,12288)        f32[48][64]          fidx 0
// qbf   [12288,19200)    bf16[48][72]         sidx 6144   (P0-P1)
// kbf   [19200,26112)    bf16[48][72]         sidx 9600
// vbf   [26112,33024)    bf16[48][72]         sidx 13056
// Wqkv  [33024,35328)    bf16 3x[16][24]      sidx 16512
// Wo    [35328,44544)    bf16[64][72]         sidx 17664
// qp    [44544,51456)    bf16[48][72]         sidx 22272  (-> o in P3+)
// kp    [51456,58368)    bf16[48][72]         sidx 25728
// vpT   [58368,65536)    bf16[64][56]         sidx 29184
// att   [12288,33792)    bf16 4x[48][56]      sidx 6144   (P2-P3, over qbf/kbf/vbf)
// out2  [51456,63744)    f32[48][64]          fidx 12864  (P4, over kp/vpT)
// xbf   [12288,19200)    bf16[48][72]         sidx 6144   (P4b+, over att)
// W1buf [19200,37632)    bf16[128][72]        sidx 9600   (FF1 halves)
// h     [37632,62976)    bf16[48][264]        sidx 18816
// W2buf [0,16896)        bf16[32][264]        sidx 0      (FF2 halves)
// ffout [16896,29184)    f32[48][64]          fidx 4224

#define QF_F   0
#define QBF_S  6144
#define KBF_S  9600
#define VBF_S  13056
#define WQKV_S 16512
#define WOB_S  17664
#define QP_S   22272
#define KP_S   25728
#define VPT_S  29184
#define ATT_S  6144
#define OUT2_F 12864
#define OBUF_S 22272
#define XBF_S  6144
#define W1B_S  9600
#define HBUF_S 18816
#define W2B_S  0
#define FFO_F  4224

__device__ __forceinline__ short f2bf(float f) {
    __hip_bfloat16 h = __float2bfloat16(f);
    return *reinterpret_cast<const short*>(&h);
}

__device__ __forceinline__ float wave_sum64(float v) {
    v += __shfl_xor(v, 1, 64);
    v += __shfl_xor(v, 2, 64);
    v += __shfl_xor(v, 4, 64);
    v += __shfl_xor(v, 8, 64);
    v += __shfl_xor(v, 16, 64);
    v += __shfl_xor(v, 32, 64);
    return v;
}

__global__ __launch_bounds__(256, 2)
void ttrans_kernel(const float* __restrict__ value,
                   const float* __restrict__ keys,
                   const float* __restrict__ query,
                   const float* __restrict__ Wv,
                   const float* __restrict__ Wk,
                   const float* __restrict__ Wq,
                   const float* __restrict__ Wo,
                   const float* __restrict__ bo,
                   const float* __restrict__ temb,
                   const float* __restrict__ ln1g,
                   const float* __restrict__ ln1b,
                   const float* __restrict__ ln2g,
                   const float* __restrict__ ln2b,
                   const float* __restrict__ W1,
                   const float* __restrict__ b1,
                   const float* __restrict__ W2,
                   const float* __restrict__ b2,
                   const int* __restrict__ tqp,
                   float* __restrict__ out)
{
    __shared__ __align__(16) unsigned char smem[65536];
    short* S16 = reinterpret_cast<short*>(smem);
    float* S32 = reinterpret_cast<float*>(smem);

    const int tid  = threadIdx.x;
    const int lane = tid & 63;
    const int w    = tid >> 6;
    const int l15  = lane & 15;
    const int lg   = lane >> 4;          // k-slice group 0..3
    const int n    = blockIdx.x;
    const int base4 = n * 768;           // float4 index base for (48*64) rows
    const int tqv  = *tqp;

    // ================= P0: load + bf16 convert =================
    {
        int r = tid >> 4, c = tid & 15;
        S16[WQKV_S + 0 * 384 + r * 24 + c] = f2bf(Wv[tid]);
        S16[WQKV_S + 1 * 384 + r * 24 + c] = f2bf(Wk[tid]);
        S16[WQKV_S + 2 * 384 + r * 24 + c] = f2bf(Wq[tid]);
    }
    for (int i4 = tid; i4 < 1024; i4 += 256) {      // Wo 64x64
        float4 wv4 = ((const float4*)Wo)[i4];
        int r = i4 >> 4, c0 = (i4 & 15) * 4;
        short* d = &S16[WOB_S + r * 72 + c0];
        d[0] = f2bf(wv4.x); d[1] = f2bf(wv4.y); d[2] = f2bf(wv4.z); d[3] = f2bf(wv4.w);
    }
    for (int i4 = tid; i4 < 768; i4 += 256) {       // q,k,v 48x64 each
        int t = i4 >> 4;
        int c0 = (i4 & 15) * 4;
        int ti = ((tqv % TN) + TN + t) % TN;
        float4 te = ((const float4*)temb)[ti * 16 + (i4 & 15)];
        float4 qv = ((const float4*)query)[base4 + i4];
        float4 kv = ((const float4*)keys)[base4 + i4];
        float4 vv = ((const float4*)value)[base4 + i4];
        qv.x += te.x; qv.y += te.y; qv.z += te.z; qv.w += te.w;
        kv.x += te.x; kv.y += te.y; kv.z += te.z; kv.w += te.w;
        *reinterpret_cast<float4*>(&S32[QF_F + t * 64 + c0]) = qv;
        short* dq = &S16[QBF_S + t * 72 + c0];
        dq[0] = f2bf(qv.x); dq[1] = f2bf(qv.y); dq[2] = f2bf(qv.z); dq[3] = f2bf(qv.w);
        short* dk = &S16[KBF_S + t * 72 + c0];
        dk[0] = f2bf(kv.x); dk[1] = f2bf(kv.y); dk[2] = f2bf(kv.z); dk[3] = f2bf(kv.w);
        short* dv = &S16[VBF_S + t * 72 + c0];
        dv[0] = f2bf(vv.x); dv[1] = f2bf(vv.y); dv[2] = f2bf(vv.z); dv[3] = f2bf(vv.w);
    }
    __syncthreads();

    // ================= P1: per-head projections (K=16 padded to 32) ==========
    for (int idx = w; idx < 36; idx += 4) {
        int mat = idx / 12;                   // 0=v 1=k 2=q
        int rem = idx % 12;
        int hh = rem / 3, rt = rem % 3;
        int srcS = (mat == 0) ? VBF_S : (mat == 1) ? KBF_S : QBF_S;
        bf16x8 a = {}; bf16x8 b = {};
        if (lane < 32) {
            int kl = lg * 8;                  // 0 or 8
            a = *reinterpret_cast<const bf16x8*>(&S16[srcS + (rt * 16 + l15) * 72 + hh * 16 + kl]);
            b = *reinterpret_cast<const bf16x8*>(&S16[WQKV_S + mat * 384 + l15 * 24 + kl]);
        }
        f32x4 c = {0.f, 0.f, 0.f, 0.f};
        c = __builtin_amdgcn_mfma_f32_16x16x32_bf16(a, b, c, 0, 0, 0);
        int eo = hh * 16 + l15;
        if (mat == 0) {
            #pragma unroll
            for (int r = 0; r < 4; ++r)
                S16[VPT_S + eo * 56 + (rt * 16 + lg * 4 + r)] = f2bf(c[r]);
        } else {
            int dstS = (mat == 1) ? KP_S : QP_S;
            #pragma unroll
            for (int r = 0; r < 4; ++r)
                S16[dstS + (rt * 16 + lg * 4 + r) * 72 + eo] = f2bf(c[r]);
        }
    }
    __syncthreads();

    // ================= P2: energy + softmax (wave w = head w) =================
    {
        const int hh = w;
        for (int rt = 0; rt < 3; ++rt) {
            bf16x8 a = {};
            if (lane < 32)
                a = *reinterpret_cast<const bf16x8*>(&S16[QP_S + (rt * 16 + l15) * 72 + hh * 16 + lg * 8]);
            f32x4 e0 = {0.f,0.f,0.f,0.f}, e1 = {0.f,0.f,0.f,0.f}, e2v = {0.f,0.f,0.f,0.f};
            {
                bf16x8 b = {};
                if (lane < 32)
                    b = *reinterpret_cast<const bf16x8*>(&S16[KP_S + (0 * 16 + l15) * 72 + hh * 16 + lg * 8]);
                e0 = __builtin_amdgcn_mfma_f32_16x16x32_bf16(a, b, e0, 0, 0, 0);
            }
            {
                bf16x8 b = {};
                if (lane < 32)
                    b = *reinterpret_cast<const bf16x8*>(&S16[KP_S + (1 * 16 + l15) * 72 + hh * 16 + lg * 8]);
                e1 = __builtin_amdgcn_mfma_f32_16x16x32_bf16(a, b, e1, 0, 0, 0);
            }
            {
                bf16x8 b = {};
                if (lane < 32)
                    b = *reinterpret_cast<const bf16x8*>(&S16[KP_S + (2 * 16 + l15) * 72 + hh * 16 + lg * 8]);
                e2v = __builtin_amdgcn_mfma_f32_16x16x32_bf16(a, b, e2v, 0, 0, 0);
            }
            #pragma unroll
            for (int r = 0; r < 4; ++r) {
                int t = rt * 16 + lg * 4 + r;
                float v0 = (0 * 16 + l15 <= t) ? e0[r] : -1e6f;
                float v1 = (1 * 16 + l15 <= t) ? e1[r] : -1e6f;
                float v2 = (2 * 16 + l15 <= t) ? e2v[r] : -1e6f;
                v0 = fminf(5.f, fmaxf(-5.f, v0 * 0.125f));
                v1 = fminf(5.f, fmaxf(-5.f, v1 * 0.125f));
                v2 = fminf(5.f, fmaxf(-5.f, v2 * 0.125f));
                float m = fmaxf(v0, fmaxf(v1, v2));
                m = fmaxf(m, __shfl_xor(m, 1, 64));
                m = fmaxf(m, __shfl_xor(m, 2, 64));
                m = fmaxf(m, __shfl_xor(m, 4, 64));
                m = fmaxf(m, __shfl_xor(m, 8, 64));
                float p0 = __expf(v0 - m), p1 = __expf(v1 - m), p2 = __expf(v2 - m);
                float s = p0 + p1 + p2;
                s += __shfl_xor(s, 1, 64);
                s += __shfl_xor(s, 2, 64);
                s += __shfl_xor(s, 4, 64);
                s += __shfl_xor(s, 8, 64);
                float inv = 1.f / s;
                S16[ATT_S + hh * 2688 + t * 56 +  0 + l15] = f2bf(p0 * inv);
                S16[ATT_S + hh * 2688 + t * 56 + 16 + l15] = f2bf(p1 * inv);
                S16[ATT_S + hh * 2688 + t * 56 + 32 + l15] = f2bf(p2 * inv);
            }
        }
    }
    __syncthreads();

    // ================= P3: PV (wave w = head w), K=48 padded to 64 ============
    {
        const int hh = w;
        for (int mt = 0; mt < 3; ++mt) {
            f32x4 c = {0.f,0.f,0.f,0.f};
            {   // k 0..31
                bf16x8 a = *reinterpret_cast<const bf16x8*>(&S16[ATT_S + hh * 2688 + (mt * 16 + l15) * 56 + lg * 8]);
                bf16x8 b = *reinterpret_cast<const bf16x8*>(&S16[VPT_S + (hh * 16 + l15) * 56 + lg * 8]);
                c = __builtin_amdgcn_mfma_f32_16x16x32_bf16(a, b, c, 0, 0, 0);
            }
            {   // k 32..47 (lanes 32-63 are k>=48: zero)
                bf16x8 a = {}; bf16x8 b = {};
                if (lane < 32) {
                    a = *reinterpret_cast<const bf16x8*>(&S16[ATT_S + hh * 2688 + (mt * 16 + l15) * 56 + 32 + lg * 8]);
                    b = *reinterpret_cast<const bf16x8*>(&S16[VPT_S + (hh * 16 + l15) * 56 + 32 + lg * 8]);
                }
                c = __builtin_amdgcn_mfma_f32_16x16x32_bf16(a, b, c, 0, 0, 0);
            }
            #pragma unroll
            for (int r = 0; r < 4; ++r)
                S16[OBUF_S + (mt * 16 + lg * 4 + r) * 72 + hh * 16 + l15] = f2bf(c[r]);
        }
    }
    __syncthreads();

    // ================= P4: out2 = o @ Wo^T ====================================
    for (int idx = w; idx < 12; idx += 4) {
        int mt = idx >> 2, nt = idx & 3;
        f32x4 c = {0.f,0.f,0.f,0.f};
        #pragma unroll
        for (int ks = 0; ks < 2; ++ks) {
            bf16x8 a = *reinterpret_cast<const bf16x8*>(&S16[OBUF_S + (mt * 16 + l15) * 72 + ks * 32 + lg * 8]);
            bf16x8 b = *reinterpret_cast<const bf16x8*>(&S16[WOB_S + (nt * 16 + l15) * 72 + ks * 32 + lg * 8]);
            c = __builtin_amdgcn_mfma_f32_16x16x32_bf16(a, b, c, 0, 0, 0);
        }
        #pragma unroll
        for (int r = 0; r < 4; ++r)
            S32[OUT2_F + (mt * 16 + lg * 4 + r) * 64 + nt * 16 + l15] = c[r];
    }
    __syncthreads();

    // ================= P4b: LN1 (wave-per-row), keep x residual in regs =======
    float xres[12];
    {
        const float g1 = ln1g[lane], be1 = ln1b[lane], bor = bo[lane];
        #pragma unroll
        for (int it = 0; it < 12; ++it) {
            int t = w * 12 + it;
            float vv = S32[OUT2_F + t * 64 + lane] + bor + S32[QF_F + t * 64 + lane];
            float mu = wave_sum64(vv) * (1.0f / 64.0f);
            float d = vv - mu;
            float var = wave_sum64(d * d) * (1.0f / 64.0f);
            float x = d * rsqrtf(var + EPSF) * g1 + be1;
            xres[it] = x;
            S16[XBF_S + t * 72 + lane] = f2bf(x);
        }
    }
    __syncthreads();

    // ================= P5: FF1 in two 128-col halves ==========================
    for (int hb = 0; hb < 2; ++hb) {
        for (int i4 = tid; i4 < 2048; i4 += 256) {          // W1 half: 128x64
            float4 wv4 = ((const float4*)W1)[hb * 2048 + i4];
            int j = i4 >> 4, c0 = (i4 & 15) * 4;
            short* d = &S16[W1B_S + j * 72 + c0];
            d[0] = f2bf(wv4.x); d[1] = f2bf(wv4.y); d[2] = f2bf(wv4.z); d[3] = f2bf(wv4.w);
        }
        __syncthreads();
        for (int idx = w; idx < 24; idx += 4) {
            int mt = idx / 8, nt = idx % 8;
            f32x4 c = {0.f,0.f,0.f,0.f};
            #pragma unroll
            for (int ks = 0; ks < 2; ++ks) {
                bf16x8 a = *reinterpret_cast<const bf16x8*>(&S16[XBF_S + (mt * 16 + l15) * 72 + ks * 32 + lg * 8]);
                bf16x8 b = *reinterpret_cast<const bf16x8*>(&S16[W1B_S + (nt * 16 + l15) * 72 + ks * 32 + lg * 8]);
                c = __builtin_amdgcn_mfma_f32_16x16x32_bf16(a, b, c, 0, 0, 0);
            }
            int j = hb * 128 + nt * 16 + l15;
            float b1v = b1[j];
            #pragma unroll
            for (int r = 0; r < 4; ++r)
                S16[HBUF_S + (mt * 16 + lg * 4 + r) * 264 + j] = f2bf(fmaxf(c[r] + b1v, 0.f));
        }
        __syncthreads();
    }

    // ================= P6: FF2 in two 32-row (output-dim) halves ==============
    for (int nb = 0; nb < 2; ++nb) {
        for (int i4 = tid; i4 < 2048; i4 += 256) {          // W2 rows nb*32..+31
            float4 wv4 = ((const float4*)W2)[nb * 2048 + i4];
            int e = i4 >> 6, c0 = (i4 & 63) * 4;
            short* d = &S16[W2B_S + e * 264 + c0];
            d[0] = f2bf(wv4.x); d[1] = f2bf(wv4.y); d[2] = f2bf(wv4.z); d[3] = f2bf(wv4.w);
        }
        __syncthreads();
        for (int idx = w; idx < 6; idx += 4) {
            int mt = idx >> 1, ntl = idx & 1;
            f32x4 c = {0.f,0.f,0.f,0.f};
            #pragma unroll
            for (int ks = 0; ks < 8; ++ks) {
                bf16x8 a = *reinterpret_cast<const bf16x8*>(&S16[HBUF_S + (mt * 16 + l15) * 264 + ks * 32 + lg * 8]);
                bf16x8 b = *reinterpret_cast<const bf16x8*>(&S16[W2B_S + (ntl * 16 + l15) * 264 + ks * 32 + lg * 8]);
                c = __builtin_amdgcn_mfma_f32_16x16x32_bf16(a, b, c, 0, 0, 0);
            }
            int e = nb * 32 + ntl * 16 + l15;
            float b2v = b2[e];
            #pragma unroll
            for (int r = 0; r < 4; ++r)
                S32[FFO_F + (mt * 16 + lg * 4 + r) * 64 + e] = c[r] + b2v;
        }
        __syncthreads();
    }

    // ================= P7: LN2 + store ========================================
    {
        const float g2 = ln2g[lane], be2 = ln2b[lane];
        #pragma unroll
        for (int it = 0; it < 12; ++it) {
            int t = w * 12 + it;
            float vv = S32[FFO_F + t * 64 + lane] + xres[it];
            float mu = wave_sum64(vv) * (1.0f / 64.0f);
            float d = vv - mu;
            float var = wave_sum64(d * d) * (1.0f / 64.0f);
            out[(size_t)n * 3072 + t * 64 + lane] = d * rsqrtf(var + EPSF) * g2 + be2;
        }
    }
}

extern "C" void kernel_launch(void* const* d_in, const int* in_sizes, int n_in,
                              void* d_out, int out_size, void* d_ws, size_t ws_size,
                              hipStream_t stream) {
    const float* value = (const float*)d_in[0];
    const float* keys  = (const float*)d_in[1];
    const float* query = (const float*)d_in[2];
    const float* Wv    = (const float*)d_in[3];
    const float* Wk    = (const float*)d_in[4];
    const float* Wq    = (const float*)d_in[5];
    const float* Wo    = (const float*)d_in[6];
    const float* bo    = (const float*)d_in[7];
    const float* temb  = (const float*)d_in[8];
    const float* ln1g  = (const float*)d_in[9];
    const float* ln1b  = (const float*)d_in[10];
    const float* ln2g  = (const float*)d_in[11];
    const float* ln2b  = (const float*)d_in[12];
    const float* W1    = (const float*)d_in[13];
    const float* b1    = (const float*)d_in[14];
    const float* W2    = (const float*)d_in[15];
    const float* b2    = (const float*)d_in[16];
    const int*   tq    = (const int*)d_in[17];
    float* outp = (float*)d_out;

    hipLaunchKernelGGL(ttrans_kernel, dim3(NSEQ), dim3(256), 0, stream,
                       value, keys, query, Wv, Wk, Wq, Wo, bo, temb,
                       ln1g, ln1b, ln2g, ln2b, W1, b1, W2, b2, tq, outp);
}

// Round 3
// 97.822 us; speedup vs baseline: 14.0194x; 1.9356x over previous
//
#include <hip/hip_runtime.h>
#include <hip/hip_bf16.h>
#include <math.h>

#define NSEQ 4096
#define TN 288
#define EPSF 1e-5f

typedef short bf16x8 __attribute__((ext_vector_type(8)));
typedef float f32x4 __attribute__((ext_vector_type(4)));

// ---- d_ws layout (shorts): preconverted bf16 weights ----
#define WSV 0        // Wv 16x16
#define WSK 256      // Wk 16x16
#define WSQ 512      // Wq 16x16
#define WSO 768      // Wo 64x64 row-major
#define WS1 4864     // W1 256x64 row-major
#define WS2 21248    // W2 64x256 row-major
#define WS_TOT 37632 // shorts

// ---- LDS pool (40704 bytes -> rounds to 40KB -> 4 blocks/CU) ----
// short-index constants (byte ranges in comments):
#define QBF_S  0      // qbf  48x72 bf16   [0,6912)        P0->P1
#define KBF_S  3456   // kbf  48x72        [6912,13824)    P0->P1
#define VBF_S  6912   // vbf  48x72        [13824,20736)   P0->P1
#define QP_S   10368  // qp   48x72        [20736,27648)   P1->P2 (per-head cols)
#define KP_S   13824  // kp   48x72        [27648,34560)   P1->P2 (per-head cols)
#define VPT_S  17280  // vpT  64x48        [34560,40704)   P1->P3 (per-head rows)
#define ATT_S  0      // att  4x 48x48     [0,18432)       P2->P3 (per-head, over qbf/kbf/vbf)
#define O_S    10368  // o    48x72        [20736,27648)   P3->P4 (over qp, per-head cols)
#define OUT2_F 6912   // out2 48x64 f32    [27648,39936)   P4->LN1 (over kp/vpT)
#define XBF_S  0      // xbf  48x72        [0,6912)        LN1->FF1, LN2 residual
#define HB_S   3456   // h    48x264       [6912,32256)    FF1->FF2
#define FFO_S  16128  // ffo  48x72        [32256,39168)   FF2->LN2

__device__ __forceinline__ unsigned short f2bf_u(float f) {
    __hip_bfloat16 h = __float2bfloat16(f);
    return *reinterpret_cast<const unsigned short*>(&h);
}
__device__ __forceinline__ unsigned int pk2(float a, float b) {
    return (unsigned int)f2bf_u(a) | ((unsigned int)f2bf_u(b) << 16);
}
__device__ __forceinline__ float bits2f(unsigned int u) { return __uint_as_float(u); }

__device__ __forceinline__ float halfsum(float v) {   // sum over 32-lane half
    v += __shfl_xor(v, 1);
    v += __shfl_xor(v, 2);
    v += __shfl_xor(v, 4);
    v += __shfl_xor(v, 8);
    v += __shfl_xor(v, 16);
    return v;
}

// ---------- prologue: f32 -> bf16 weight conversion into d_ws ----------
__global__ void wconv_kernel(const float* __restrict__ Wv, const float* __restrict__ Wk,
                             const float* __restrict__ Wq, const float* __restrict__ Wo,
                             const float* __restrict__ W1, const float* __restrict__ W2,
                             short* __restrict__ ws) {
    int i = blockIdx.x * 256 + threadIdx.x;   // 0..37631
    float v;
    if (i < 256)        v = Wv[i];
    else if (i < 512)   v = Wk[i - 256];
    else if (i < 768)   v = Wq[i - 512];
    else if (i < 4864)  v = Wo[i - 768];
    else if (i < 21248) v = W1[i - 4864];
    else                v = W2[i - 21248];
    ws[i] = (short)f2bf_u(v);
}

__global__ __launch_bounds__(256, 4)
void ttrans_kernel(const float* __restrict__ value,
                   const float* __restrict__ keys,
                   const float* __restrict__ query,
                   const float* __restrict__ bo,
                   const float* __restrict__ temb,
                   const float* __restrict__ ln1g,
                   const float* __restrict__ ln1b,
                   const float* __restrict__ ln2g,
                   const float* __restrict__ ln2b,
                   const float* __restrict__ pb1,
                   const float* __restrict__ pb2,
                   const short* __restrict__ ws,
                   const int* __restrict__ tqp,
                   float* __restrict__ out)
{
    __shared__ __align__(16) unsigned char smem[40704];
    short* S16 = reinterpret_cast<short*>(smem);
    float* S32 = reinterpret_cast<float*>(smem);

    const int tid  = threadIdx.x;
    const int lane = tid & 63;
    const int w    = tid >> 6;           // wave 0..3 (= head in P1-P3)
    const int l15  = lane & 15;
    const int lg   = lane >> 4;
    const int n    = blockIdx.x;
    const size_t gbase = (size_t)n * 3072;
    const int tqv  = *tqp;
    const int c0   = (lane & 31) * 2;    // pair-col for P0/LN phases
    const int sub  = lane >> 5;

    // ================= P0: load q,k,v (+temb), bf16 to LDS, q residual in regs
    float2 qres2[6];
    {
        #pragma unroll
        for (int it2 = 0; it2 < 6; ++it2) {
            int t = w * 12 + it2 * 2 + sub;
            int ti = ((tqv % TN) + TN + t) % TN;
            float2 tv = *reinterpret_cast<const float2*>(&temb[ti * 64 + c0]);
            float2 qv = *reinterpret_cast<const float2*>(&query[gbase + t * 64 + c0]);
            float2 kv = *reinterpret_cast<const float2*>(&keys [gbase + t * 64 + c0]);
            float2 vv = *reinterpret_cast<const float2*>(&value[gbase + t * 64 + c0]);
            float q0 = qv.x + tv.x, q1 = qv.y + tv.y;
            float k0 = kv.x + tv.x, k1 = kv.y + tv.y;
            qres2[it2] = make_float2(q0, q1);
            *reinterpret_cast<unsigned int*>(&S16[QBF_S + t * 72 + c0]) = pk2(q0, q1);
            *reinterpret_cast<unsigned int*>(&S16[KBF_S + t * 72 + c0]) = pk2(k0, k1);
            *reinterpret_cast<unsigned int*>(&S16[VBF_S + t * 72 + c0]) = pk2(vv.x, vv.y);
        }
    }
    __syncthreads();

    // ================= P1: per-head projections, wave w = head w (9 MFMAs)
    {
        const int hh = w;
        const int srcS[3] = {VBF_S, KBF_S, QBF_S};
        const int wsb[3]  = {WSV, WSK, WSQ};
        bf16x8 bW[3];
        #pragma unroll
        for (int mat = 0; mat < 3; ++mat) {
            bf16x8 b = {};
            if (lane < 32) b = *reinterpret_cast<const bf16x8*>(&ws[wsb[mat] + l15 * 16 + lg * 8]);
            bW[mat] = b;
        }
        #pragma unroll
        for (int mat = 0; mat < 3; ++mat) {
            #pragma unroll
            for (int rt = 0; rt < 3; ++rt) {
                bf16x8 a = {};
                if (lane < 32)
                    a = *reinterpret_cast<const bf16x8*>(&S16[srcS[mat] + (rt * 16 + l15) * 72 + hh * 16 + lg * 8]);
                f32x4 c = {0.f, 0.f, 0.f, 0.f};
                c = __builtin_amdgcn_mfma_f32_16x16x32_bf16(a, bW[mat], c, 0, 0, 0);
                if (mat == 0) {
                    #pragma unroll
                    for (int r = 0; r < 4; ++r)
                        S16[VPT_S + (hh * 16 + l15) * 48 + rt * 16 + lg * 4 + r] = (short)f2bf_u(c[r]);
                } else {
                    int dst = (mat == 1) ? KP_S : QP_S;
                    #pragma unroll
                    for (int r = 0; r < 4; ++r)
                        S16[dst + (rt * 16 + lg * 4 + r) * 72 + hh * 16 + l15] = (short)f2bf_u(c[r]);
                }
            }
        }
    }
    __syncthreads();   // att (P2) overlays qbf/kbf/vbf read cross-head in P1

    // ================= P2: energy + softmax, wave w = head w (no barrier after:
    //                  att/vpT/qp/kp/o are all per-head regions)
    {
        const int hh = w;
        bf16x8 bK0 = {}, bK1 = {}, bK2 = {};
        if (lane < 32) {
            bK0 = *reinterpret_cast<const bf16x8*>(&S16[KP_S + ( 0 + l15) * 72 + hh * 16 + lg * 8]);
            bK1 = *reinterpret_cast<const bf16x8*>(&S16[KP_S + (16 + l15) * 72 + hh * 16 + lg * 8]);
            bK2 = *reinterpret_cast<const bf16x8*>(&S16[KP_S + (32 + l15) * 72 + hh * 16 + lg * 8]);
        }
        #pragma unroll
        for (int rt = 0; rt < 3; ++rt) {
            bf16x8 a = {};
            if (lane < 32)
                a = *reinterpret_cast<const bf16x8*>(&S16[QP_S + (rt * 16 + l15) * 72 + hh * 16 + lg * 8]);
            f32x4 e0 = {0.f,0.f,0.f,0.f}, e1 = {0.f,0.f,0.f,0.f}, e2 = {0.f,0.f,0.f,0.f};
            e0 = __builtin_amdgcn_mfma_f32_16x16x32_bf16(a, bK0, e0, 0, 0, 0);
            e1 = __builtin_amdgcn_mfma_f32_16x16x32_bf16(a, bK1, e1, 0, 0, 0);
            e2 = __builtin_amdgcn_mfma_f32_16x16x32_bf16(a, bK2, e2, 0, 0, 0);
            #pragma unroll
            for (int r = 0; r < 4; ++r) {
                int t = rt * 16 + lg * 4 + r;
                float v0 = ( 0 + l15 <= t) ? e0[r] : -1e6f;
                float v1 = (16 + l15 <= t) ? e1[r] : -1e6f;
                float v2 = (32 + l15 <= t) ? e2[r] : -1e6f;
                v0 = fminf(5.f, fmaxf(-5.f, v0 * 0.125f));
                v1 = fminf(5.f, fmaxf(-5.f, v1 * 0.125f));
                v2 = fminf(5.f, fmaxf(-5.f, v2 * 0.125f));
                float m = fmaxf(v0, fmaxf(v1, v2));
                m = fmaxf(m, __shfl_xor(m, 1));
                m = fmaxf(m, __shfl_xor(m, 2));
                m = fmaxf(m, __shfl_xor(m, 4));
                m = fmaxf(m, __shfl_xor(m, 8));
                float p0 = __expf(v0 - m), p1 = __expf(v1 - m), p2 = __expf(v2 - m);
                float s = p0 + p1 + p2;
                s += __shfl_xor(s, 1);
                s += __shfl_xor(s, 2);
                s += __shfl_xor(s, 4);
                s += __shfl_xor(s, 8);
                float inv = 1.f / s;
                S16[ATT_S + hh * 2304 + t * 48 +  0 + l15] = (short)f2bf_u(p0 * inv);
                S16[ATT_S + hh * 2304 + t * 48 + 16 + l15] = (short)f2bf_u(p1 * inv);
                S16[ATT_S + hh * 2304 + t * 48 + 32 + l15] = (short)f2bf_u(p2 * inv);
            }
        }
    }
    // no barrier: P3 consumes only this wave's att/vpT

    // ================= P3: PV, wave w = head w (K=48 padded to 64)
    {
        const int hh = w;
        bf16x8 v0 = *reinterpret_cast<const bf16x8*>(&S16[VPT_S + (hh * 16 + l15) * 48 + lg * 8]);
        bf16x8 v1 = {};
        if (lane < 32)
            v1 = *reinterpret_cast<const bf16x8*>(&S16[VPT_S + (hh * 16 + l15) * 48 + 32 + lg * 8]);
        #pragma unroll
        for (int mt = 0; mt < 3; ++mt) {
            f32x4 c = {0.f,0.f,0.f,0.f};
            bf16x8 a0 = *reinterpret_cast<const bf16x8*>(&S16[ATT_S + hh * 2304 + (mt * 16 + l15) * 48 + lg * 8]);
            c = __builtin_amdgcn_mfma_f32_16x16x32_bf16(a0, v0, c, 0, 0, 0);
            bf16x8 a1 = {};
            if (lane < 32)
                a1 = *reinterpret_cast<const bf16x8*>(&S16[ATT_S + hh * 2304 + (mt * 16 + l15) * 48 + 32 + lg * 8]);
            c = __builtin_amdgcn_mfma_f32_16x16x32_bf16(a1, v1, c, 0, 0, 0);
            #pragma unroll
            for (int r = 0; r < 4; ++r)
                S16[O_S + (mt * 16 + lg * 4 + r) * 72 + hh * 16 + l15] = (short)f2bf_u(c[r]);
        }
    }
    __syncthreads();   // P4 reads all heads' o columns

    // ================= P4: out2 = o @ Wo^T  (wave w owns output cols w*16..+15)
    {
        bf16x8 bO0 = *reinterpret_cast<const bf16x8*>(&ws[WSO + (w * 16 + l15) * 64 + lg * 8]);
        bf16x8 bO1 = *reinterpret_cast<const bf16x8*>(&ws[WSO + (w * 16 + l15) * 64 + 32 + lg * 8]);
        #pragma unroll
        for (int mt = 0; mt < 3; ++mt) {
            bf16x8 a0 = *reinterpret_cast<const bf16x8*>(&S16[O_S + (mt * 16 + l15) * 72 + lg * 8]);
            bf16x8 a1 = *reinterpret_cast<const bf16x8*>(&S16[O_S + (mt * 16 + l15) * 72 + 32 + lg * 8]);
            f32x4 c = {0.f,0.f,0.f,0.f};
            c = __builtin_amdgcn_mfma_f32_16x16x32_bf16(a0, bO0, c, 0, 0, 0);
            c = __builtin_amdgcn_mfma_f32_16x16x32_bf16(a1, bO1, c, 0, 0, 0);
            #pragma unroll
            for (int r = 0; r < 4; ++r)
                S32[OUT2_F + (mt * 16 + lg * 4 + r) * 64 + w * 16 + l15] = c[r];
        }
    }
    __syncthreads();

    // ================= LN1: wave-per-row (2 cols/lane), x -> xbf
    {
        float2 bo2  = *reinterpret_cast<const float2*>(&bo[c0]);
        float2 g12  = *reinterpret_cast<const float2*>(&ln1g[c0]);
        float2 be12 = *reinterpret_cast<const float2*>(&ln1b[c0]);
        #pragma unroll
        for (int it2 = 0; it2 < 6; ++it2) {
            int t = w * 12 + it2 * 2 + sub;
            float2 o2 = *reinterpret_cast<const float2*>(&S32[OUT2_F + t * 64 + c0]);
            float v0 = o2.x + bo2.x + qres2[it2].x;
            float v1 = o2.y + bo2.y + qres2[it2].y;
            float mu = halfsum(v0 + v1) * (1.f / 64.f);
            float d0 = v0 - mu, d1 = v1 - mu;
            float var = halfsum(d0 * d0 + d1 * d1) * (1.f / 64.f);
            float rs = rsqrtf(var + EPSF);
            float x0 = d0 * rs * g12.x + be12.x;
            float x1 = d1 * rs * g12.y + be12.y;
            *reinterpret_cast<unsigned int*>(&S16[XBF_S + t * 72 + c0]) = pk2(x0, x1);
        }
    }
    __syncthreads();

    // ================= FF1: h = relu(x @ W1^T + b1), wave w owns j16 = w*4..w*4+3
    {
        bf16x8 aX[3][2];
        #pragma unroll
        for (int mt = 0; mt < 3; ++mt) {
            aX[mt][0] = *reinterpret_cast<const bf16x8*>(&S16[XBF_S + (mt * 16 + l15) * 72 + lg * 8]);
            aX[mt][1] = *reinterpret_cast<const bf16x8*>(&S16[XBF_S + (mt * 16 + l15) * 72 + 32 + lg * 8]);
        }
        #pragma unroll
        for (int jj = 0; jj < 4; ++jj) {
            int j16 = w * 4 + jj;
            bf16x8 b0 = *reinterpret_cast<const bf16x8*>(&ws[WS1 + (j16 * 16 + l15) * 64 + lg * 8]);
            bf16x8 b1 = *reinterpret_cast<const bf16x8*>(&ws[WS1 + (j16 * 16 + l15) * 64 + 32 + lg * 8]);
            float b1v = pb1[j16 * 16 + l15];
            #pragma unroll
            for (int mt = 0; mt < 3; ++mt) {
                f32x4 c = {0.f,0.f,0.f,0.f};
                c = __builtin_amdgcn_mfma_f32_16x16x32_bf16(aX[mt][0], b0, c, 0, 0, 0);
                c = __builtin_amdgcn_mfma_f32_16x16x32_bf16(aX[mt][1], b1, c, 0, 0, 0);
                #pragma unroll
                for (int r = 0; r < 4; ++r)
                    S16[HB_S + (mt * 16 + lg * 4 + r) * 264 + j16 * 16 + l15] =
                        (short)f2bf_u(fmaxf(c[r] + b1v, 0.f));
            }
        }
    }
    __syncthreads();

    // ================= FF2: ff = h @ W2^T + b2, wave w owns output cols w*16..+15
    {
        bf16x8 bw[8];
        #pragma unroll
        for (int ks = 0; ks < 8; ++ks)
            bw[ks] = *reinterpret_cast<const bf16x8*>(&ws[WS2 + (w * 16 + l15) * 256 + ks * 32 + lg * 8]);
        float b2v = pb2[w * 16 + l15];
        #pragma unroll
        for (int mt = 0; mt < 3; ++mt) {
            f32x4 c = {0.f,0.f,0.f,0.f};
            #pragma unroll
            for (int ks = 0; ks < 8; ++ks) {
                bf16x8 a = *reinterpret_cast<const bf16x8*>(&S16[HB_S + (mt * 16 + l15) * 264 + ks * 32 + lg * 8]);
                c = __builtin_amdgcn_mfma_f32_16x16x32_bf16(a, bw[ks], c, 0, 0, 0);
            }
            #pragma unroll
            for (int r = 0; r < 4; ++r)
                S16[FFO_S + (mt * 16 + lg * 4 + r) * 72 + w * 16 + l15] = (short)f2bf_u(c[r] + b2v);
        }
    }
    __syncthreads();

    // ================= LN2 + store (2 cols/lane)
    {
        float2 g22  = *reinterpret_cast<const float2*>(&ln2g[c0]);
        float2 be22 = *reinterpret_cast<const float2*>(&ln2b[c0]);
        #pragma unroll
        for (int it2 = 0; it2 < 6; ++it2) {
            int t = w * 12 + it2 * 2 + sub;
            unsigned int fp = *reinterpret_cast<const unsigned int*>(&S16[FFO_S + t * 72 + c0]);
            unsigned int xp = *reinterpret_cast<const unsigned int*>(&S16[XBF_S + t * 72 + c0]);
            float v0 = bits2f(fp << 16) + bits2f(xp << 16);
            float v1 = bits2f(fp & 0xffff0000u) + bits2f(xp & 0xffff0000u);
            float mu = halfsum(v0 + v1) * (1.f / 64.f);
            float d0 = v0 - mu, d1 = v1 - mu;
            float var = halfsum(d0 * d0 + d1 * d1) * (1.f / 64.f);
            float rs = rsqrtf(var + EPSF);
            float y0 = d0 * rs * g22.x + be22.x;
            float y1 = d1 * rs * g22.y + be22.y;
            *reinterpret_cast<float2*>(&out[gbase + t * 64 + c0]) = make_float2(y0, y1);
        }
    }
}

extern "C" void kernel_launch(void* const* d_in, const int* in_sizes, int n_in,
                              void* d_out, int out_size, void* d_ws, size_t ws_size,
                              hipStream_t stream) {
    const float* value = (const float*)d_in[0];
    const float* keys  = (const float*)d_in[1];
    const float* query = (const float*)d_in[2];
    const float* Wv    = (const float*)d_in[3];
    const float* Wk    = (const float*)d_in[4];
    const float* Wq    = (const float*)d_in[5];
    const float* Wo    = (const float*)d_in[6];
    const float* bo    = (const float*)d_in[7];
    const float* temb  = (const float*)d_in[8];
    const float* ln1g  = (const float*)d_in[9];
    const float* ln1b  = (const float*)d_in[10];
    const float* ln2g  = (const float*)d_in[11];
    const float* ln2b  = (const float*)d_in[12];
    const float* W1    = (const float*)d_in[13];
    const float* b1    = (const float*)d_in[14];
    const float* W2    = (const float*)d_in[15];
    const float* b2    = (const float*)d_in[16];
    const int*   tq    = (const int*)d_in[17];
    float* outp = (float*)d_out;
    short* ws = (short*)d_ws;

    hipLaunchKernelGGL(wconv_kernel, dim3(147), dim3(256), 0, stream,
                       Wv, Wk, Wq, Wo, W1, W2, ws);
    hipLaunchKernelGGL(ttrans_kernel, dim3(NSEQ), dim3(256), 0, stream,
                       value, keys, query, bo, temb,
                       ln1g, ln1b, ln2g, ln2b, b1, b2, ws, tq, outp);
}